// Round 4
// baseline (884.229 us; speedup 1.0000x reference)
//
#include <hip/hip_runtime.h>

#define NN 256
#define CC 512
#define OO 1024
#define BB 64

#define F_QR 0.1f
#define F_KR 0.1f
#define F_SVE 0.1f

__device__ inline float4 bn4(float4 v, float sc, float hh) {
  return make_float4(v.x * sc + hh, v.y * sc + hh, v.z * sc + hh, v.w * sc + hh);
}

// ---------------- K0: pad rel rows 511 -> 512 (enables aligned float4 rel loads)
__global__ void k_relpad(const float* __restrict__ rel, float* __restrict__ relp) {
  const int row = blockIdx.x;
  const int t = threadIdx.x;
  for (int u = t; u < 511; u += 256) relp[row * 512 + u] = rel[row * 511 + u];
  if (t == 0) relp[row * 512 + 511] = 0.f;
}

// ---------------- K0b: windowed correlation tables from rel ----------------
// W[c][c'][i] = sum_{d=i}^{i+255} R[c,d]*R[c',d];  T[c][i] = sum_{d=i}^{i+255} R[c,d]
// half 0: R = relp rows 0..31 (q_emb) -> Wq/Tq ; half 1: rows 32..63 (k_emb) -> W2/T2
__global__ __launch_bounds__(256) void k_wtab(const float* __restrict__ relp,
                                              float* __restrict__ Wq, float* __restrict__ Tq,
                                              float* __restrict__ W2, float* __restrict__ T2) {
  const int c = blockIdx.x, cp = blockIdx.y, half = blockIdx.z;
  if (cp < c) return;
  float* W = half ? W2 : Wq;
  float* T = half ? T2 : Tq;
  __shared__ float Rc[512], Rc2[512];
  const int t = threadIdx.x;
  for (int d = t; d < 512; d += 256) {
    Rc[d] = relp[(half * 32 + c) * 512 + d];
    Rc2[d] = relp[(half * 32 + cp) * 512 + d];
  }
  __syncthreads();
  float acc = 0.f, tacc = 0.f;
  for (int d = 0; d < 256; ++d) {
    float a = Rc[t + d];
    acc += a * Rc2[t + d];
    tacc += a;
  }
  W[(c * 32 + cp) * 256 + t] = acc;
  if (cp != c) W[(cp * 32 + c) * 256 + t] = acc;
  else T[c * 256 + t] = tacc;
}

// ---------------- K1: qkv[b][o][n] = sum_c W[o][c] * x[b][n][c] ----------------
__global__ __launch_bounds__(256) void k_qkv_gemm(const float* __restrict__ x,
                                                  const float* __restrict__ w,
                                                  float* __restrict__ qkv) {
  const int b = blockIdx.z, ot = blockIdx.y, nt = blockIdx.x;
  const int o0 = ot * 128, n0 = nt * 128;
  __shared__ float As[32][132];
  __shared__ float Bs[32][132];
  const int t = threadIdx.x;
  const int to = t >> 4, tn = t & 15;
  float acc[8][8];
#pragma unroll
  for (int i = 0; i < 8; ++i)
#pragma unroll
    for (int j = 0; j < 8; ++j) acc[i][j] = 0.f;

  const float* wbase = w + (size_t)o0 * CC;
  const float* xbase = x + (size_t)b * NN * CC + (size_t)n0 * CC;

  for (int c0 = 0; c0 < CC; c0 += 32) {
#pragma unroll
    for (int r = 0; r < 4; ++r) {
      int f = t + 256 * r;
      int row = f >> 3, cq = f & 7;
      float4 w4 = *(const float4*)(wbase + (size_t)row * CC + c0 + cq * 4);
      As[cq * 4 + 0][row] = w4.x; As[cq * 4 + 1][row] = w4.y;
      As[cq * 4 + 2][row] = w4.z; As[cq * 4 + 3][row] = w4.w;
      float4 x4 = *(const float4*)(xbase + (size_t)row * CC + c0 + cq * 4);
      Bs[cq * 4 + 0][row] = x4.x; Bs[cq * 4 + 1][row] = x4.y;
      Bs[cq * 4 + 2][row] = x4.z; Bs[cq * 4 + 3][row] = x4.w;
    }
    __syncthreads();
#pragma unroll
    for (int kk = 0; kk < 32; ++kk) {
      float a[8], bb[8];
      *(float4*)&a[0] = *(const float4*)&As[kk][to * 8];
      *(float4*)&a[4] = *(const float4*)&As[kk][to * 8 + 4];
      *(float4*)&bb[0] = *(const float4*)&Bs[kk][tn * 8];
      *(float4*)&bb[4] = *(const float4*)&Bs[kk][tn * 8 + 4];
#pragma unroll
      for (int i = 0; i < 8; ++i)
#pragma unroll
        for (int j = 0; j < 8; ++j) acc[i][j] += a[i] * bb[j];
    }
    __syncthreads();
  }
#pragma unroll
  for (int i = 0; i < 8; ++i) {
    float* dst = qkv + ((size_t)b * OO + o0 + to * 8 + i) * NN + n0 + tn * 8;
    float4 v0 = {acc[i][0], acc[i][1], acc[i][2], acc[i][3]};
    float4 v1 = {acc[i][4], acc[i][5], acc[i][6], acc[i][7]};
    *(float4*)dst = v0;
    *(float4*)(dst + 4) = v1;
  }
}

// ---------------- K2: per-channel BN scale/shift for qkv ----------------
__global__ __launch_bounds__(256) void k_qkv_stats(const float* __restrict__ qkv,
                                                   const float* __restrict__ gq,
                                                   const float* __restrict__ bq,
                                                   float* __restrict__ qs,
                                                   float* __restrict__ qh) {
  const int o = blockIdx.x;
  const int t = threadIdx.x;
  float s = 0.f, ss = 0.f;
  for (int b = 0; b < BB; ++b) {
    float v = qkv[((size_t)b * OO + o) * NN + t];
    s += v; ss += v * v;
  }
#pragma unroll
  for (int m = 1; m < 64; m <<= 1) { s += __shfl_xor(s, m); ss += __shfl_xor(ss, m); }
  __shared__ float rs[4], rss[4];
  int wv = t >> 6;
  if ((t & 63) == 0) { rs[wv] = s; rss[wv] = ss; }
  __syncthreads();
  if (t == 0) {
    s = rs[0] + rs[1] + rs[2] + rs[3];
    ss = rss[0] + rss[1] + rss[2] + rss[3];
    const float inv = 1.f / (float)(BB * NN);
    float m = s * inv;
    float var = ss * inv - m * m;
    float r = rsqrtf(var + 1e-5f);
    float sc = gq[o] * r;
    qs[o] = sc;
    qh[o] = bq[o] - m * sc;
  }
}

// ---------------- K3a: per-(b,g) Gram matrices of BN'd q and k + row sums ----
__global__ __launch_bounds__(256) void k_stats_qk(const float* __restrict__ qkv,
                                                  const float* __restrict__ qs,
                                                  const float* __restrict__ qh,
                                                  float* __restrict__ Gq, float* __restrict__ Gk,
                                                  float* __restrict__ Sq, float* __restrict__ Sk) {
  const int b = blockIdx.x, g = blockIdx.y;
  __shared__ float qsm[32 * 132];
  __shared__ float ksm[32 * 132];
  const int t = threadIdx.x;
  const int tc = t & 15, tu = t >> 4;
  float gq[2][2] = {{0.f, 0.f}, {0.f, 0.f}}, gk[2][2] = {{0.f, 0.f}, {0.f, 0.f}};
  float rsum = 0.f;

  for (int panel = 0; panel < 2; ++panel) {
    __syncthreads();
#pragma unroll
    for (int r = 0; r < 4; ++r) {
      int f = t + 256 * r;
      int row = f >> 5, i4 = f & 31;
      int oq = g * 128 + row;
      float4 v = *(const float4*)(qkv + ((size_t)b * OO + oq) * NN + panel * 128 + i4 * 4);
      *(float4*)&qsm[row * 132 + i4 * 4] = bn4(v, qs[oq], qh[oq]);
      int ok = oq + 32;
      float4 u = *(const float4*)(qkv + ((size_t)b * OO + ok) * NN + panel * 128 + i4 * 4);
      *(float4*)&ksm[row * 132 + i4 * 4] = bn4(u, qs[ok], qh[ok]);
    }
    __syncthreads();
#pragma unroll 8
    for (int s = 0; s < 32; ++s) {
      int i = s * 4;
      float4 a0 = *(const float4*)&qsm[(2 * tc) * 132 + i];
      float4 a1 = *(const float4*)&qsm[(2 * tc + 1) * 132 + i];
      float4 b0 = *(const float4*)&qsm[(2 * tu) * 132 + i];
      float4 b1 = *(const float4*)&qsm[(2 * tu + 1) * 132 + i];
      gq[0][0] += a0.x * b0.x + a0.y * b0.y + a0.z * b0.z + a0.w * b0.w;
      gq[0][1] += a0.x * b1.x + a0.y * b1.y + a0.z * b1.z + a0.w * b1.w;
      gq[1][0] += a1.x * b0.x + a1.y * b0.y + a1.z * b0.z + a1.w * b0.w;
      gq[1][1] += a1.x * b1.x + a1.y * b1.y + a1.z * b1.z + a1.w * b1.w;
      float4 c0 = *(const float4*)&ksm[(2 * tc) * 132 + i];
      float4 c1 = *(const float4*)&ksm[(2 * tc + 1) * 132 + i];
      float4 d0 = *(const float4*)&ksm[(2 * tu) * 132 + i];
      float4 d1 = *(const float4*)&ksm[(2 * tu + 1) * 132 + i];
      gk[0][0] += c0.x * d0.x + c0.y * d0.y + c0.z * d0.z + c0.w * d0.w;
      gk[0][1] += c0.x * d1.x + c0.y * d1.y + c0.z * d1.z + c0.w * d1.w;
      gk[1][0] += c1.x * d0.x + c1.y * d0.y + c1.z * d0.z + c1.w * d0.w;
      gk[1][1] += c1.x * d1.x + c1.y * d1.y + c1.z * d1.z + c1.w * d1.w;
    }
    if (t < 32) {
      for (int i = 0; i < 128; ++i) rsum += qsm[t * 132 + i];
    } else if (t < 64) {
      for (int i = 0; i < 128; ++i) rsum += ksm[(t - 32) * 132 + i];
    }
  }
  const size_t base = ((size_t)b * 8 + g) * 1024;
#pragma unroll
  for (int u = 0; u < 2; ++u)
#pragma unroll
    for (int v = 0; v < 2; ++v) {
      Gq[base + (2 * tc + u) * 32 + 2 * tu + v] = gq[u][v];
      Gk[base + (2 * tc + u) * 32 + 2 * tu + v] = gk[u][v];
    }
  if (t < 32) Sq[((size_t)b * 8 + g) * 32 + t] = rsum;
  else if (t < 64) Sk[((size_t)b * 8 + g) * 32 + (t - 32)] = rsum;
}

// ---------------- K3b: qk-term stats from Grams ----------------
__global__ __launch_bounds__(256) void k_qk_reduce(const float* __restrict__ Gq,
                                                   const float* __restrict__ Gk,
                                                   const float* __restrict__ Sq,
                                                   const float* __restrict__ Sk,
                                                   float* __restrict__ simacc) {
  const int g = blockIdx.x;
  const int t = threadIdx.x;
  float s2 = 0.f;
  for (int f = t; f < 65536; f += 256) {
    int b = f >> 10, p = f & 1023;
    size_t idx = ((size_t)b * 8 + g) * 1024 + p;
    s2 += Gq[idx] * Gk[idx];
  }
  float s1 = 0.f;
  for (int f = t; f < 2048; f += 256) {
    int b = f >> 5, c = f & 31;
    size_t idx = ((size_t)b * 8 + g) * 32 + c;
    s1 += Sq[idx] * Sk[idx];
  }
#pragma unroll
  for (int m = 1; m < 64; m <<= 1) { s1 += __shfl_xor(s1, m); s2 += __shfl_xor(s2, m); }
  __shared__ float a1[4], a2[4];
  int w = t >> 6;
  if ((t & 63) == 0) { a1[w] = s1; a2[w] = s2; }
  __syncthreads();
  if (t == 0) {
    simacc[g] = a1[0] + a1[1] + a1[2] + a1[3];
    simacc[24 + g] = a2[0] + a2[1] + a2[2] + a2[3];
  }
}

// ---------------- K3c: qr/kr-term stats via windowed-correlation identity ----
// term sum  = sum_{c,i} (sum_b x[c,i]) * T[c,i]
// term sum2 = sum_{i} sum_{cc'} (sum_b x[c,i]x[c',i]) * W[cc',i]
__global__ __launch_bounds__(256) void k_stats_win(const float* __restrict__ qkv,
                                                   const float* __restrict__ relW,
                                                   const float* __restrict__ relT,
                                                   const float* __restrict__ qs,
                                                   const float* __restrict__ qh,
                                                   float* __restrict__ simacc,
                                                   int rowbase, int term, float F) {
  __shared__ float Ws[32 * 289];   // [c][c'*9 + i]
  __shared__ float qsm[32 * 9];    // [c][i]
  const int i0 = blockIdx.x * 8;
  const int g = blockIdx.y;
  const int b0 = blockIdx.z * 16;
  const int t = threadIdx.x;
  const int tc = t & 15, tu = t >> 4;

  for (int f = t; f < 8192; f += 256) {
    int p = f >> 3, il = f & 7;
    Ws[(p >> 5) * 289 + (p & 31) * 9 + il] = relW[p * 256 + i0 + il];
  }
  const int mc = t >> 3, mi = t & 7;
  const float tval = relT[mc * 256 + i0 + mi];
  const int o = g * 128 + rowbase + mc;
  const float msc = qs[o], mhh = qh[o];

  float acc[2][2][8];
#pragma unroll
  for (int u = 0; u < 2; ++u)
#pragma unroll
    for (int v = 0; v < 2; ++v)
#pragma unroll
      for (int i = 0; i < 8; ++i) acc[u][v][i] = 0.f;
  float msum = 0.f;

  for (int b = b0; b < b0 + 16; ++b) {
    __syncthreads();
    float val = qkv[((size_t)b * OO + o) * NN + i0 + mi] * msc + mhh;
    qsm[mc * 9 + mi] = val;
    msum += val;
    __syncthreads();
    float r0[8], r1[8], c0[8], c1[8];
#pragma unroll
    for (int i = 0; i < 8; ++i) {
      r0[i] = qsm[(2 * tc) * 9 + i];
      r1[i] = qsm[(2 * tc + 1) * 9 + i];
      c0[i] = qsm[(2 * tu) * 9 + i];
      c1[i] = qsm[(2 * tu + 1) * 9 + i];
    }
#pragma unroll
    for (int i = 0; i < 8; ++i) {
      acc[0][0][i] += r0[i] * c0[i];
      acc[0][1][i] += r0[i] * c1[i];
      acc[1][0][i] += r1[i] * c0[i];
      acc[1][1][i] += r1[i] * c1[i];
    }
  }
  float s2 = 0.f;
#pragma unroll
  for (int u = 0; u < 2; ++u)
#pragma unroll
    for (int v = 0; v < 2; ++v)
#pragma unroll
      for (int i = 0; i < 8; ++i)
        s2 += acc[u][v][i] * Ws[(2 * tc + u) * 289 + (2 * tu + v) * 9 + i];
  float s1 = msum * tval;

#pragma unroll
  for (int m = 1; m < 64; m <<= 1) { s1 += __shfl_xor(s1, m); s2 += __shfl_xor(s2, m); }
  __shared__ float a1[4], a2[4];
  int w = t >> 6;
  if ((t & 63) == 0) { a1[w] = s1; a2[w] = s2; }
  __syncthreads();
  if (t == 0) {
    atomicAdd(&simacc[term * 8 + g], F * (a1[0] + a1[1] + a1[2] + a1[3]));
    atomicAdd(&simacc[24 + term * 8 + g], F * F * (a2[0] + a2[1] + a2[2] + a2[3]));
  }
}

// ---------------- finalize sim BN coefficients ----------------
__global__ void k_sim_finalize(const float* __restrict__ simacc,
                               const float* __restrict__ gs,
                               const float* __restrict__ bs,
                               float* __restrict__ simscale,
                               float* __restrict__ simshift) {
  const int t = threadIdx.x;
  __shared__ float sh[24];
  if (t < 24) {
    const float inv = 1.f / (64.f * 256.f * 256.f);
    float m = simacc[t] * inv;
    float var = simacc[24 + t] * inv - m * m;
    float a = gs[t] * rsqrtf(var + 1e-5f);
    simscale[t] = a;
    sh[t] = bs[t] - m * a;
  }
  __syncthreads();
  if (t < 8) simshift[t] = sh[t] + sh[8 + t] + sh[16 + t];
}

// ---------------- pass2: sim + softmax + sv/sve ----------------
__global__ __launch_bounds__(256) void k_pass2(const float* __restrict__ qkv,
                                               const float* __restrict__ relp,
                                               const float* __restrict__ qs,
                                               const float* __restrict__ qh,
                                               const float* __restrict__ simscale,
                                               float* __restrict__ svbuf,
                                               float* __restrict__ svebuf) {
  __shared__ float qt[2048];
  __shared__ float kt[8192];  // reused as vt in phase B

  const int it = blockIdx.x, bg = blockIdx.y;
  const int b = bg >> 3, g = bg & 7, i0 = it * 64;
  const int t = threadIdx.x, rg = t >> 4, cg = t & 15;
  const float aQK = simscale[g];
  const float aQR = F_QR * simscale[8 + g];
  const float aKR = F_KR * simscale[16 + g];
  // NOTE: the BN shift is uniform per group => softmax-invariant => dropped.

#pragma unroll
  for (int r = 0; r < 2; ++r) {
    int f = t + 256 * r;
    int row = f >> 4, c4 = f & 15;
    int o = g * 128 + row;
    float sc = qs[o], hh = qh[o];
    float4 v = *(const float4*)(qkv + ((size_t)b * OO + o) * NN + i0 + c4 * 4);
    *(float4*)&qt[row * 64 + c4 * 4] = bn4(v, sc, hh);
  }
#pragma unroll
  for (int r = 0; r < 8; ++r) {
    int f = t + 256 * r;
    int row = f >> 6, c4 = f & 63;
    int o = g * 128 + 32 + row;
    float sc = qs[o], hh = qh[o];
    float4 v = *(const float4*)(qkv + ((size_t)b * OO + o) * NN + c4 * 4);
    *(float4*)&kt[row * 256 + c4 * 4] = bn4(v, sc, hh);
  }
  __syncthreads();

  float p[4][4][4];
#pragma unroll
  for (int di = 0; di < 4; ++di)
#pragma unroll
    for (int q = 0; q < 4; ++q)
#pragma unroll
      for (int dj = 0; dj < 4; ++dj) p[di][q][dj] = 0.f;

  for (int c = 0; c < 32; ++c) {
    float q4[4];
    *(float4*)q4 = *(const float4*)&qt[c * 64 + rg * 4];
    float k16[4][4];
#pragma unroll
    for (int q = 0; q < 4; ++q) *(float4*)k16[q] = *(const float4*)&kt[c * 256 + q * 64 + cg * 4];
    float q4a[4], q4r[4];
#pragma unroll
    for (int di = 0; di < 4; ++di) { q4a[di] = q4[di] * aQK; q4r[di] = q4[di] * aQR; }
#pragma unroll
    for (int di = 0; di < 4; ++di)
#pragma unroll
      for (int q = 0; q < 4; ++q)
#pragma unroll
        for (int dj = 0; dj < 4; ++dj) p[di][q][dj] += q4a[di] * k16[q][dj];
#pragma unroll
    for (int q = 0; q < 4; ++q) {
      const float* rp = relp + c * 512 + (i0 + rg * 4 - cg * 4 - 64 * q + 252);
      float rq[8];
      *(float4*)&rq[0] = *(const float4*)rp;
      *(float4*)&rq[4] = *(const float4*)(rp + 4);
#pragma unroll
      for (int di = 0; di < 4; ++di)
#pragma unroll
        for (int dj = 0; dj < 4; ++dj) p[di][q][dj] += q4r[di] * rq[di - dj + 3];
    }
#pragma unroll
    for (int q = 0; q < 4; ++q)
#pragma unroll
      for (int dj = 0; dj < 4; ++dj) k16[q][dj] *= aKR;
#pragma unroll
    for (int q = 0; q < 4; ++q) {
      const float* rp = relp + (32 + c) * 512 + (64 * q + cg * 4 - i0 - rg * 4 + 252);
      float rk[8];
      *(float4*)&rk[0] = *(const float4*)rp;
      *(float4*)&rk[4] = *(const float4*)(rp + 4);
#pragma unroll
      for (int di = 0; di < 4; ++di)
#pragma unroll
        for (int dj = 0; dj < 4; ++dj) p[di][q][dj] += k16[q][dj] * rk[dj - di + 3];
    }
  }

#pragma unroll
  for (int di = 0; di < 4; ++di) {
    float m = -1e30f;
#pragma unroll
    for (int q = 0; q < 4; ++q)
#pragma unroll
      for (int dj = 0; dj < 4; ++dj) m = fmaxf(m, p[di][q][dj]);
#pragma unroll
    for (int k = 1; k < 16; k <<= 1) m = fmaxf(m, __shfl_xor(m, k));
    float s = 0.f;
#pragma unroll
    for (int q = 0; q < 4; ++q)
#pragma unroll
      for (int dj = 0; dj < 4; ++dj) { p[di][q][dj] = __expf(p[di][q][dj] - m); s += p[di][q][dj]; }
#pragma unroll
    for (int k = 1; k < 16; k <<= 1) s += __shfl_xor(s, k);
    float invs = 1.f / s;
#pragma unroll
    for (int q = 0; q < 4; ++q)
#pragma unroll
      for (int dj = 0; dj < 4; ++dj) p[di][q][dj] *= invs;
  }
  __syncthreads();

  for (int chunk = 0; chunk < 2; ++chunk) {
#pragma unroll
    for (int r = 0; r < 8; ++r) {
      int f = t + 256 * r;
      int row = f >> 6, c4 = f & 63;
      int o = g * 128 + 64 + chunk * 32 + row;
      float sc = qs[o], hh = qh[o];
      float4 v = *(const float4*)(qkv + ((size_t)b * OO + o) * NN + c4 * 4);
      *(float4*)&kt[row * 256 + c4 * 4] = bn4(v, sc, hh);
    }
    __syncthreads();
    for (int c = 0; c < 32; ++c) {
      float v16[4][4];
#pragma unroll
      for (int q = 0; q < 4; ++q) *(float4*)v16[q] = *(const float4*)&kt[c * 256 + q * 64 + cg * 4];
      float sp[4], se[4];
#pragma unroll
      for (int di = 0; di < 4; ++di) {
        float s = 0.f;
#pragma unroll
        for (int q = 0; q < 4; ++q)
#pragma unroll
          for (int dj = 0; dj < 4; ++dj) s += p[di][q][dj] * v16[q][dj];
        sp[di] = s;
      }
      float rv[4][8];
#pragma unroll
      for (int q = 0; q < 4; ++q) {
        const float* rp = relp + (64 + chunk * 32 + c) * 512 + (i0 + rg * 4 - cg * 4 - 64 * q + 252);
        *(float4*)&rv[q][0] = *(const float4*)rp;
        *(float4*)&rv[q][4] = *(const float4*)(rp + 4);
      }
#pragma unroll
      for (int di = 0; di < 4; ++di) {
        float s = 0.f;
#pragma unroll
        for (int q = 0; q < 4; ++q)
#pragma unroll
          for (int dj = 0; dj < 4; ++dj) s += p[di][q][dj] * rv[q][di - dj + 3];
        se[di] = s;
      }
#pragma unroll
      for (int di = 0; di < 4; ++di)
#pragma unroll
        for (int k = 1; k < 16; k <<= 1) {
          sp[di] += __shfl_xor(sp[di], k);
          se[di] += __shfl_xor(se[di], k);
        }
      if (cg == 0) {
        float4 o1 = {sp[0], sp[1], sp[2], sp[3]};
        *(float4*)(svbuf + ((size_t)(b * 512 + g * 64 + chunk * 32 + c)) * NN + i0 + rg * 4) = o1;
        float4 o2 = {se[0] * F_SVE, se[1] * F_SVE, se[2] * F_SVE, se[3] * F_SVE};
        *(float4*)(svebuf + ((size_t)(b * 512 + g * 64 + chunk * 32 + c)) * NN + i0 + rg * 4) = o2;
      }
    }
    __syncthreads();
  }
}

// ---------------- K6: final BN stats over sv / sve ----------------
__global__ __launch_bounds__(256) void k_out_stats(const float* __restrict__ svbuf,
                                                   const float* __restrict__ svebuf,
                                                   const float* __restrict__ go,
                                                   const float* __restrict__ bo,
                                                   float* __restrict__ osc,
                                                   float* __restrict__ osh) {
  const int bid = blockIdx.x;
  const int arr = bid >> 9, pch = bid & 511;
  const float* buf = arr ? svebuf : svbuf;
  const int t = threadIdx.x;
  float s = 0.f, ss = 0.f;
  for (int b = 0; b < BB; ++b) {
    float v = buf[((size_t)b * 512 + pch) * NN + t];
    s += v; ss += v * v;
  }
#pragma unroll
  for (int m = 1; m < 64; m <<= 1) { s += __shfl_xor(s, m); ss += __shfl_xor(ss, m); }
  __shared__ float rs[4], rss[4];
  int wv = t >> 6;
  if ((t & 63) == 0) { rs[wv] = s; rss[wv] = ss; }
  __syncthreads();
  if (t == 0) {
    s = rs[0] + rs[1] + rs[2] + rs[3];
    ss = rss[0] + rss[1] + rss[2] + rss[3];
    const float inv = 1.f / 16384.f;
    float m = s * inv;
    float var = ss * inv - m * m;
    float r = rsqrtf(var + 1e-5f);
    int o = pch * 2 + arr;
    float sc = go[o] * r;
    osc[bid] = sc;
    osh[bid] = bo[o] - m * sc;
  }
}

// ---------------- K7: combine ----------------
__global__ __launch_bounds__(256) void k_final(const float* __restrict__ svbuf,
                                               const float* __restrict__ svebuf,
                                               const float* __restrict__ osc,
                                               const float* __restrict__ osh,
                                               float* __restrict__ out) {
  const size_t f = (size_t)blockIdx.x * 256 + threadIdx.x;  // float4 index
  const int pch = (int)((f >> 6) & 511);
  float4 a = ((const float4*)svbuf)[f];
  float4 e = ((const float4*)svebuf)[f];
  float s1 = osc[pch], h1 = osh[pch];
  float s2 = osc[512 + pch], h2 = osh[512 + pch];
  float hh = h1 + h2;
  float4 o;
  o.x = a.x * s1 + e.x * s2 + hh;
  o.y = a.y * s1 + e.y * s2 + hh;
  o.z = a.z * s1 + e.z * s2 + hh;
  o.w = a.w * s1 + e.w * s2 + hh;
  ((float4*)out)[f] = o;
}

extern "C" void kernel_launch(void* const* d_in, const int* in_sizes, int n_in,
                              void* d_out, int out_size, void* d_ws, size_t ws_size,
                              hipStream_t stream) {
  const float* x     = (const float*)d_in[0];
  const float* w     = (const float*)d_in[1];
  const float* rel   = (const float*)d_in[2];
  const float* g_qkv = (const float*)d_in[3];
  const float* b_qkv = (const float*)d_in[4];
  const float* g_sim = (const float*)d_in[5];
  const float* b_sim = (const float*)d_in[6];
  const float* g_out = (const float*)d_in[7];
  const float* b_out = (const float*)d_in[8];

  float* ws = (float*)d_ws;
  float* qkv      = ws;                       // 16,777,216
  float* sv       = qkv + 16777216;           // 8,388,608
  float* sve      = sv + 8388608;             // 8,388,608
  float* qs       = sve + 8388608;            // 1024
  float* qh       = qs + 1024;                // 1024
  float* simacc   = qh + 1024;                // 48
  float* simscale = simacc + 48;              // 24
  float* simshift = simscale + 24;            // 8
  float* osc      = simshift + 8;             // 1024
  float* osh      = osc + 1024;               // 1024

  // Scratch tables live in d_out's dead region (d_out is only written by
  // k_final, which runs after every reader below; k_final overwrites all of it).
  float* ob   = (float*)d_out;
  float* relp = ob;                 // 65,536
  float* Wq   = ob + 65536;         // 262,144
  float* W2   = ob + 327680;        // 262,144
  float* Tq   = ob + 589824;        // 8,192
  float* T2   = ob + 598016;        // 8,192
  float* Gq   = ob + 606208;        // 524,288
  float* Gk   = ob + 1130496;       // 524,288
  float* Sq   = ob + 1654784;       // 16,384
  float* Sk   = ob + 1671168;       // 16,384  (end 1,687,552 < 8,388,608)

  hipMemsetAsync(simacc, 0, 48 * sizeof(float), stream);

  k_relpad<<<128, 256, 0, stream>>>(rel, relp);
  k_wtab<<<dim3(32, 32, 2), 256, 0, stream>>>(relp, Wq, Tq, W2, T2);
  k_qkv_gemm<<<dim3(2, 8, 64), 256, 0, stream>>>(x, w, qkv);
  k_qkv_stats<<<1024, 256, 0, stream>>>(qkv, g_qkv, b_qkv, qs, qh);
  k_stats_qk<<<dim3(64, 8), 256, 0, stream>>>(qkv, qs, qh, Gq, Gk, Sq, Sk);
  k_qk_reduce<<<8, 256, 0, stream>>>(Gq, Gk, Sq, Sk, simacc);
  k_stats_win<<<dim3(32, 8, 4), 256, 0, stream>>>(qkv, Wq, Tq, qs, qh, simacc, 0, 1, F_QR);
  k_stats_win<<<dim3(32, 8, 4), 256, 0, stream>>>(qkv, W2, T2, qs, qh, simacc, 32, 2, F_KR);
  k_sim_finalize<<<1, 32, 0, stream>>>(simacc, g_sim, b_sim, simscale, simshift);
  k_pass2<<<dim3(4, 512), 256, 0, stream>>>(qkv, relp, qs, qh, simscale, sv, sve);
  k_out_stats<<<1024, 256, 0, stream>>>(sv, sve, g_out, b_out, osc, osh);
  k_final<<<8192, 256, 0, stream>>>(sv, sve, osc, osh, (float*)d_out);
}